// Round 3
// baseline (231.323 us; speedup 1.0000x reference)
//
#include <hip/hip_runtime.h>
#include <hip/hip_cooperative_groups.h>

constexpr int N_NODES = 50000;
constexpr int N_EDGES = 800000;
constexpr int D = 64;

constexpr int NREG = 256;    // destination regions (one block each in phase B)
constexpr int RSZ = 196;     // nodes per region (256*196 = 50176 >= 50000)
constexpr int EPB = 3136;    // edges per block in phase A (mult of 4)
constexpr int NBINB = 256;   // binning grid width (= NREG blocks)
constexpr int CELLCAP = 48;  // per-(region,block) cell cap; mean 12.25, P(>48)~1e-15
constexpr int SCSTR = 52;    // scell LDS stride in words: bank=(20r+p)%32 spread, 208B (16B-aligned)
constexpr int RECAP = 4608;  // per-region edge cap; mean 3125, sigma 56
constexpr int MT = 13;       // ceil(196/16) M-tiles for the MFMA phase

// Workspace layout:
//   cnt2 [NREG*NBINB] ints          at int 0     (256 KB)
//   rbuf [NREG*NBINB*CELLCAP] ints  at int 65536 (12.6 MB, 192B cells)
//   hb   [N_NODES*D] ushorts        after rbuf   (6.4 MB)
constexpr int WS_CNT2 = 0;
constexpr int WS_RBUF = NREG * NBINB;  // 65536
constexpr size_t WS_HB_BYTE = (size_t)(WS_RBUF + (size_t)NREG * NBINB * CELLCAP) * 4;

typedef __attribute__((ext_vector_type(8))) short short8v;
typedef __attribute__((ext_vector_type(4))) float f32x4;

__device__ __forceinline__ ushort to_bf16(float x) {
  unsigned u = __float_as_uint(x);
  u += 0x7FFF + ((u >> 16) & 1);  // RNE
  return (ushort)(u >> 16);
}
__device__ __forceinline__ float bf_lo(unsigned u) {
  return __uint_as_float(u << 16);
}
__device__ __forceinline__ float bf_hi(unsigned u) {
  return __uint_as_float(u & 0xFFFF0000u);
}
__device__ __forceinline__ float bf_val(ushort h) {
  return __uint_as_float(((unsigned)h) << 16);
}

// Single cooperative kernel: phase A = bf16 convert + edge binning (was
// prep_kernel), grid.sync(), phase B = sort + gather + MFMA matvec (was
// gin_kernel). Removes one dispatch boundary + inter-kernel L2 drain.
// Phase A LDS staging now stride-52 (bank=(20r+p)%32) to kill the p%32
// bank aliasing of the old r*64+p layout.
__global__ __launch_bounds__(1024) void fused_kernel(
    const float* __restrict__ feat, const int* __restrict__ src,
    const int* __restrict__ dst, const float* __restrict__ W,
    const float* __restrict__ b, const float* __restrict__ eps,
    int* __restrict__ cnt2, unsigned* __restrict__ rbuf,
    ushort* __restrict__ hb, float* __restrict__ out) {
  __shared__ __align__(16) char smem[61440];  // 60 KB pool, phases overlay
  int tid = threadIdx.x, blk = blockIdx.x;

  // ========================= PHASE A: convert + bin =========================
  {
    int* cur = reinterpret_cast<int*>(smem);                    // 256 ints
    unsigned* scell = reinterpret_cast<unsigned*>(smem) + 256;  // 256*52 words
    if (tid < NREG) cur[tid] = 0;

    const float4* feat4 = reinterpret_cast<const float4*>(feat);
    int e0 = blk * EPB + tid * 4;
    bool valid = (tid * 4 < EPB) && (e0 + 4 <= N_EDGES);
    int4 d4 = {0, 0, 0, 0}, s4 = {0, 0, 0, 0};
    if (valid) {
      d4 = *reinterpret_cast<const int4*>(dst + e0);
      s4 = *reinterpret_cast<const int4*>(src + e0);
    }

    // bf16 conversion: grid-stride over 800000 float4s.
    for (int t = blk * 1024 + tid; t < N_NODES * D / 4; t += NBINB * 1024) {
      float4 f = feat4[t];
      ushort4 h;
      h.x = to_bf16(f.x); h.y = to_bf16(f.y);
      h.z = to_bf16(f.z); h.w = to_bf16(f.w);
      *reinterpret_cast<ushort4*>(hb + t * 4) = h;
    }
    __syncthreads();

    if (valid) {
      const int dd[4] = {d4.x, d4.y, d4.z, d4.w};
      const int ss[4] = {s4.x, s4.y, s4.z, s4.w};
#pragma unroll
      for (int k = 0; k < 4; ++k) {
        int r = dd[k] / RSZ;  // magic-mul
        unsigned pk = ((unsigned)(dd[k] - r * RSZ) << 16) | (unsigned)ss[k];
        int p = atomicAdd(&cur[r], 1);
        if (p < CELLCAP) scell[r * SCSTR + p] = pk;
      }
    }
    __syncthreads();

    {  // Coalesced flush: 4 threads per region-cell, uint4 stores.
      int cell = tid >> 2, sub = tid & 3;
      int c = cur[cell];
      if (c > CELLCAP) c = CELLCAP;
      unsigned* gp = rbuf + (size_t)(cell * NBINB + blk) * CELLCAP;
      const unsigned* sp = scell + cell * SCSTR;
      for (int i = sub * 4; i < c; i += 16)
        *reinterpret_cast<uint4*>(gp + i) = *reinterpret_cast<const uint4*>(sp + i);
    }
    if (tid < NREG) {
      int c = cur[tid];
      cnt2[tid * NBINB + blk] = (c > CELLCAP) ? CELLCAP : c;
    }
  }

  __threadfence();  // device-scope: publish rbuf/cnt2/hb across XCD L2s
  cooperative_groups::this_grid().sync();

  // ========================= PHASE B: sort + gather + MFMA ==================
  int r = blk;
  int lane = tid & 63, wv = tid >> 6;

  // LDS carve (overlays phase A; all offsets 16B-aligned):
  unsigned* ebuf = reinterpret_cast<unsigned*>(smem);          // [RECAP] 18432 B, dead after B7
  ushort* rstH = reinterpret_cast<ushort*>(smem);              // [208][72] 29952 B (aliases ebuf)
  ushort* sorted = reinterpret_cast<ushort*>(smem + 29952);    // 9216 B
  ushort* WbH = reinterpret_cast<ushort*>(smem + 39168);       // 8192 B
  ushort* WbL = reinterpret_cast<ushort*>(smem + 47360);       // 8192 B
  float* b_lds = reinterpret_cast<float*>(smem + 55552);       // 256 B
  int* cellstart = reinterpret_cast<int*>(smem + 55808);       // 257 ints
  int* hist = reinterpret_cast<int*>(smem + 56848);            // 196 ints
  int* nstart = reinterpret_cast<int*>(smem + 57632);          // 197 ints
  int* cursor = reinterpret_cast<int*>(smem + 58432);          // 196 ints
  int* wsum = reinterpret_cast<int*>(smem + 59216);            // 4 ints
  int* wsum2 = reinterpret_cast<int*>(smem + 59232);           // 4 ints
  int* wq = reinterpret_cast<int*>(smem + 59248);              // 1 int

  // Pack W into MFMA B-fragment order, split hi/lo bf16 (W eff. fp32).
  // frag (tk,tn): lane l, elem e -> k=tk*32+(l>>4)*8+e, n=tn*16+(l&15).
  if (tid < 512) {
    int tile = tid >> 6, l = tid & 63;
    int tk = tile >> 2, tn = tile & 3;
    int n = tn * 16 + (l & 15);
    int kb = tk * 32 + ((l >> 4) << 3);
    const float4 w0 = *reinterpret_cast<const float4*>(W + (n << 6) + kb);
    const float4 w1 = *reinterpret_cast<const float4*>(W + (n << 6) + kb + 4);
    float wf[8] = {w0.x, w0.y, w0.z, w0.w, w1.x, w1.y, w1.z, w1.w};
    ushort hh[8], ll[8];
#pragma unroll
    for (int e = 0; e < 8; ++e) {
      ushort h = to_bf16(wf[e]);
      hh[e] = h;
      ll[e] = to_bf16(wf[e] - bf_val(h));
    }
    uint4 vH, vL;
    vH.x = hh[0] | ((unsigned)hh[1] << 16); vH.y = hh[2] | ((unsigned)hh[3] << 16);
    vH.z = hh[4] | ((unsigned)hh[5] << 16); vH.w = hh[6] | ((unsigned)hh[7] << 16);
    vL.x = ll[0] | ((unsigned)ll[1] << 16); vL.y = ll[2] | ((unsigned)ll[3] << 16);
    vL.z = ll[4] | ((unsigned)ll[5] << 16); vL.w = ll[6] | ((unsigned)ll[7] << 16);
    *reinterpret_cast<uint4*>(&WbH[(tile * 64 + l) * 8]) = vH;
    *reinterpret_cast<uint4*>(&WbL[(tile * 64 + l) * 8]) = vL;
  }
  if (tid < D) b_lds[tid] = b[tid];
  if (tid < RSZ) hist[tid] = 0;
  if (tid == 0) *wq = 0;

  // ---- scan 1: cell counts ----
  int c = (tid < NBINB) ? cnt2[r * NBINB + tid] : 0;
  int inc = c;
#pragma unroll
  for (int dlt = 1; dlt < 64; dlt <<= 1) {
    int t = __shfl_up(inc, (unsigned)dlt, 64);
    if (lane >= dlt) inc += t;
  }
  if (tid < 256 && lane == 63) wsum[wv] = inc;
  __syncthreads();  // B1
  if (tid < 256) {
    int prefix = inc - c;
    if (wv > 0) prefix += wsum[0];
    if (wv > 1) prefix += wsum[1];
    if (wv > 2) prefix += wsum[2];
    if (tid < NBINB) cellstart[tid] = prefix;
  }
  if (tid == 0) cellstart[NBINB] = wsum[0] + wsum[1] + wsum[2] + wsum[3];
  __syncthreads();  // B2
  int T = cellstart[NBINB];
  if (T > RECAP) T = RECAP;

  {  // Concatenate cells into ebuf: 4 threads per cell, uint4 loads.
    int cell = tid >> 2, sub = tid & 3;
    if (cell < NBINB) {
      int cs = cellstart[cell];
      int cc = cellstart[cell + 1] - cs;
      const unsigned* cp = rbuf + (size_t)(r * NBINB + cell) * CELLCAP;
      for (int i = sub * 4; i < cc; i += 16) {
        uint4 v = *reinterpret_cast<const uint4*>(cp + i);
        if (cs + i + 0 < T && i + 0 < cc) ebuf[cs + i + 0] = v.x;
        if (cs + i + 1 < T && i + 1 < cc) ebuf[cs + i + 1] = v.y;
        if (cs + i + 2 < T && i + 2 < cc) ebuf[cs + i + 2] = v.z;
        if (cs + i + 3 < T && i + 3 < cc) ebuf[cs + i + 3] = v.w;
      }
    }
  }
  __syncthreads();  // B3

  for (int e = tid; e < T; e += 1024) atomicAdd(&hist[ebuf[e] >> 16], 1);
  __syncthreads();  // B4

  // ---- scan 2: node counts ----
  int h = (tid < RSZ) ? hist[tid] : 0;
  int inc2 = h;
#pragma unroll
  for (int dlt = 1; dlt < 64; dlt <<= 1) {
    int t = __shfl_up(inc2, (unsigned)dlt, 64);
    if (lane >= dlt) inc2 += t;
  }
  if (tid < 256 && lane == 63) wsum2[wv] = inc2;
  __syncthreads();  // B5
  if (tid < 256) {
    int prefix = inc2 - h;
    if (wv > 0) prefix += wsum2[0];
    if (wv > 1) prefix += wsum2[1];
    if (wv > 2) prefix += wsum2[2];
    if (tid < RSZ) {
      nstart[tid] = prefix;
      cursor[tid] = prefix;
    }
  }
  if (tid == 0) nstart[RSZ] = wsum2[0] + wsum2[1] + wsum2[2] + wsum2[3];
  __syncthreads();  // B6
  for (int e = tid; e < T; e += 1024) {
    unsigned pk = ebuf[e];
    int p = atomicAdd(&cursor[pk >> 16], 1);
    sorted[p] = (ushort)(pk & 0xFFFFu);
  }
  __syncthreads();  // B7 — ebuf dead; rstH takes over the pool

  // 128 groups x 8 lanes; lane owns feature slots j8..j8+7.
  int j8 = (tid & 7) << 3;
  float s = 1.0f + eps[0];

  for (;;) {
    int n = 0;
    if ((tid & 7) == 0) n = atomicAdd(wq, 1);
    n = __shfl(n, 0, 8);
    if (n >= RSZ) break;

    int node = r * RSZ + n;
    if (node >= N_NODES) continue;  // region 255 tail (rows guarded at store)

    float acc[8];
    {  // self term in fp32
      const float4 fa = *reinterpret_cast<const float4*>(feat + (node << 6) + j8);
      const float4 fb = *reinterpret_cast<const float4*>(feat + (node << 6) + j8 + 4);
      acc[0] = s * fa.x; acc[1] = s * fa.y; acc[2] = s * fa.z; acc[3] = s * fa.w;
      acc[4] = s * fb.x; acc[5] = s * fb.y; acc[6] = s * fb.z; acc[7] = s * fb.w;
    }

    int e = nstart[n], e1 = nstart[n + 1];
    for (; e + 8 <= e1; e += 8) {
      int i0 = sorted[e + 0], i1 = sorted[e + 1], i2 = sorted[e + 2], i3 = sorted[e + 3];
      int i4_ = sorted[e + 4], i5 = sorted[e + 5], i6 = sorted[e + 6], i7 = sorted[e + 7];
      const uint4 h0 = *reinterpret_cast<const uint4*>(hb + (i0 << 6) + j8);
      const uint4 h1 = *reinterpret_cast<const uint4*>(hb + (i1 << 6) + j8);
      const uint4 h2 = *reinterpret_cast<const uint4*>(hb + (i2 << 6) + j8);
      const uint4 h3 = *reinterpret_cast<const uint4*>(hb + (i3 << 6) + j8);
      const uint4 h4 = *reinterpret_cast<const uint4*>(hb + (i4_ << 6) + j8);
      const uint4 h5 = *reinterpret_cast<const uint4*>(hb + (i5 << 6) + j8);
      const uint4 h6 = *reinterpret_cast<const uint4*>(hb + (i6 << 6) + j8);
      const uint4 h7 = *reinterpret_cast<const uint4*>(hb + (i7 << 6) + j8);
      acc[0] += (bf_lo(h0.x) + bf_lo(h1.x)) + (bf_lo(h2.x) + bf_lo(h3.x))
              + (bf_lo(h4.x) + bf_lo(h5.x)) + (bf_lo(h6.x) + bf_lo(h7.x));
      acc[1] += (bf_hi(h0.x) + bf_hi(h1.x)) + (bf_hi(h2.x) + bf_hi(h3.x))
              + (bf_hi(h4.x) + bf_hi(h5.x)) + (bf_hi(h6.x) + bf_hi(h7.x));
      acc[2] += (bf_lo(h0.y) + bf_lo(h1.y)) + (bf_lo(h2.y) + bf_lo(h3.y))
              + (bf_lo(h4.y) + bf_lo(h5.y)) + (bf_lo(h6.y) + bf_lo(h7.y));
      acc[3] += (bf_hi(h0.y) + bf_hi(h1.y)) + (bf_hi(h2.y) + bf_hi(h3.y))
              + (bf_hi(h4.y) + bf_hi(h5.y)) + (bf_hi(h6.y) + bf_hi(h7.y));
      acc[4] += (bf_lo(h0.z) + bf_lo(h1.z)) + (bf_lo(h2.z) + bf_lo(h3.z))
              + (bf_lo(h4.z) + bf_lo(h5.z)) + (bf_lo(h6.z) + bf_lo(h7.z));
      acc[5] += (bf_hi(h0.z) + bf_hi(h1.z)) + (bf_hi(h2.z) + bf_hi(h3.z))
              + (bf_hi(h4.z) + bf_hi(h5.z)) + (bf_hi(h6.z) + bf_hi(h7.z));
      acc[6] += (bf_lo(h0.w) + bf_lo(h1.w)) + (bf_lo(h2.w) + bf_lo(h3.w))
              + (bf_lo(h4.w) + bf_lo(h5.w)) + (bf_lo(h6.w) + bf_lo(h7.w));
      acc[7] += (bf_hi(h0.w) + bf_hi(h1.w)) + (bf_hi(h2.w) + bf_hi(h3.w))
              + (bf_hi(h4.w) + bf_hi(h5.w)) + (bf_hi(h6.w) + bf_hi(h7.w));
    }
    for (; e < e1; ++e) {
      int sn = sorted[e];
      const uint4 hv = *reinterpret_cast<const uint4*>(hb + (sn << 6) + j8);
      acc[0] += bf_lo(hv.x); acc[1] += bf_hi(hv.x);
      acc[2] += bf_lo(hv.y); acc[3] += bf_hi(hv.y);
      acc[4] += bf_lo(hv.z); acc[5] += bf_hi(hv.z);
      acc[6] += bf_lo(hv.w); acc[7] += bf_hi(hv.w);
    }

    // Store rst row slice as bf16 (A-fragment-friendly; row stride 144B).
    unsigned p0 = (unsigned)to_bf16(acc[0]) | ((unsigned)to_bf16(acc[1]) << 16);
    unsigned p1 = (unsigned)to_bf16(acc[2]) | ((unsigned)to_bf16(acc[3]) << 16);
    unsigned p2 = (unsigned)to_bf16(acc[4]) | ((unsigned)to_bf16(acc[5]) << 16);
    unsigned p3 = (unsigned)to_bf16(acc[6]) | ((unsigned)to_bf16(acc[7]) << 16);
    uint4 vv; vv.x = p0; vv.y = p1; vv.z = p2; vv.w = p3;
    *reinterpret_cast<uint4*>(&rstH[n * 72 + j8]) = vv;
  }
  __syncthreads();  // B8 — all rst rows written

  // ---- MFMA phase: out[196x64] = rst @ (WH + WL) + b ----
  {
    int l = tid & 63;
    int lr = l & 15, lc = l >> 4;
    for (int t = wv; t < MT * 4; t += 16) {
      int mt = t >> 2, nt = t & 3;
      int m0 = mt << 4, n0 = nt << 4;
      float bc = b_lds[n0 + lr];
      f32x4 cacc = {bc, bc, bc, bc};
#pragma unroll
      for (int tk = 0; tk < 2; ++tk) {
        short8v a = *reinterpret_cast<const short8v*>(&rstH[(m0 + lr) * 72 + tk * 32 + lc * 8]);
        short8v wh = *reinterpret_cast<const short8v*>(&WbH[((tk * 4 + nt) * 64 + l) * 8]);
        short8v wl = *reinterpret_cast<const short8v*>(&WbL[((tk * 4 + nt) * 64 + l) * 8]);
        cacc = __builtin_amdgcn_mfma_f32_16x16x32_bf16(a, wh, cacc, 0, 0, 0);
        cacc = __builtin_amdgcn_mfma_f32_16x16x32_bf16(a, wl, cacc, 0, 0, 0);
      }
#pragma unroll
      for (int rr = 0; rr < 4; ++rr) {
        int row = m0 + lc * 4 + rr;  // C/D: col=lane&15, row=(lane>>4)*4+reg (m89)
        int node = r * RSZ + row;
        if (row < RSZ && node < N_NODES)
          out[(node << 6) + n0 + lr] = cacc[rr];
      }
    }
  }
}

extern "C" void kernel_launch(void* const* d_in, const int* in_sizes, int n_in,
                              void* d_out, int out_size, void* d_ws, size_t ws_size,
                              hipStream_t stream) {
  const float* feat = (const float*)d_in[0];
  const float* W    = (const float*)d_in[1];
  const float* b    = (const float*)d_in[2];
  const float* eps  = (const float*)d_in[3];
  const int*   src  = (const int*)d_in[4];
  const int*   dst  = (const int*)d_in[5];
  float* out = (float*)d_out;

  int* ws = (int*)d_ws;
  int* cnt2      = ws + WS_CNT2;
  unsigned* rbuf = (unsigned*)(ws + WS_RBUF);
  ushort* hb     = (ushort*)((char*)d_ws + WS_HB_BYTE);

  void* args[] = {(void*)&feat, (void*)&src, (void*)&dst, (void*)&W,
                  (void*)&b,    (void*)&eps, (void*)&cnt2, (void*)&rbuf,
                  (void*)&hb,   (void*)&out};
  hipLaunchCooperativeKernel((const void*)fused_kernel, dim3(NREG), dim3(1024),
                             args, 0, stream);
}

// Round 4
// 99.551 us; speedup vs baseline: 2.3237x; 2.3237x over previous
//
#include <hip/hip_runtime.h>

constexpr int N_NODES = 50000;
constexpr int N_EDGES = 800000;
constexpr int D = 64;

constexpr int NREG = 256;    // destination regions (one gin block each)
constexpr int RSZ = 196;     // nodes per region (256*196 = 50176 >= 50000)
constexpr int EPB = 3136;    // edges per prep block (mult of 4 -> 16B-aligned int4 loads)
constexpr int NBINB = 256;   // prep grid width
constexpr int CELLCAP = 48;  // per-(region,block) cell cap; mean 12.25, P(>48)~1e-15
constexpr int SCSTR = 52;    // scell LDS stride (words): bank=(20r+p)%32, 208B, 16B-aligned
constexpr int RECAP = 4608;  // per-region edge cap; mean 3125, sigma 56

constexpr int MT = 13;  // ceil(196/16) M-tiles for the MFMA phase (rows 0..207)

// Workspace layout:
//   cnt2 [NREG*NBINB] ints          at int 0     (256 KB)
//   rbuf [NREG*NBINB*CELLCAP] ints  at int 65536 (12.6 MB, 192B cells)
//   hb   [N_NODES*D] ushorts        after rbuf   (6.4 MB)
constexpr int WS_CNT2 = 0;
constexpr int WS_RBUF = NREG * NBINB;  // 65536
constexpr size_t WS_HB_BYTE = (size_t)(WS_RBUF + (size_t)NREG * NBINB * CELLCAP) * 4;

typedef __attribute__((ext_vector_type(8))) short short8v;
typedef __attribute__((ext_vector_type(4))) float f32x4;

__device__ __forceinline__ ushort to_bf16(float x) {
  unsigned u = __float_as_uint(x);
  u += 0x7FFF + ((u >> 16) & 1);  // RNE
  return (ushort)(u >> 16);
}
__device__ __forceinline__ float bf_lo(unsigned u) {
  return __uint_as_float(u << 16);
}
__device__ __forceinline__ float bf_hi(unsigned u) {
  return __uint_as_float(u & 0xFFFF0000u);
}
__device__ __forceinline__ float bf_val(ushort h) {
  return __uint_as_float(((unsigned)h) << 16);
}

// R4: two-kernel structure reverted from the R3 fusion regression (fused
// codegen collapsed to 36 VGPR -> gather MLP died). Only the fusion-
// independent fixes are kept: scell stride-52 bank spread + CELLCAP 48.
__global__ __launch_bounds__(1024) void prep_kernel(
    const float4* __restrict__ feat4, const int* __restrict__ src,
    const int* __restrict__ dst, ushort* __restrict__ hb,
    int* __restrict__ cnt2, unsigned* __restrict__ rbuf) {
  __shared__ int cur[NREG];
  __shared__ unsigned scell[NREG * SCSTR];  // 53 KB staging, bank-spread
  int tid = threadIdx.x, blk = blockIdx.x;
  if (tid < NREG) cur[tid] = 0;

  int e0 = blk * EPB + tid * 4;
  bool valid = (tid * 4 < EPB) && (e0 + 4 <= N_EDGES);
  int4 d4 = {0, 0, 0, 0}, s4 = {0, 0, 0, 0};
  if (valid) {
    d4 = *reinterpret_cast<const int4*>(dst + e0);
    s4 = *reinterpret_cast<const int4*>(src + e0);
  }

  for (int t = blk * 1024 + tid; t < N_NODES * D / 4; t += NBINB * 1024) {
    float4 f = feat4[t];
    ushort4 h;
    h.x = to_bf16(f.x); h.y = to_bf16(f.y);
    h.z = to_bf16(f.z); h.w = to_bf16(f.w);
    *reinterpret_cast<ushort4*>(hb + t * 4) = h;
  }
  __syncthreads();

  if (valid) {
    const int dd[4] = {d4.x, d4.y, d4.z, d4.w};
    const int ss[4] = {s4.x, s4.y, s4.z, s4.w};
#pragma unroll
    for (int k = 0; k < 4; ++k) {
      int r = dd[k] / RSZ;  // magic-mul
      unsigned pk = ((unsigned)(dd[k] - r * RSZ) << 16) | (unsigned)ss[k];
      int p = atomicAdd(&cur[r], 1);
      if (p < CELLCAP) scell[r * SCSTR + p] = pk;
    }
  }
  __syncthreads();

  {  // Coalesced flush: 4 threads per region-cell, uint4 stores (192B cells).
    int cell = tid >> 2, sub = tid & 3;
    int c = cur[cell];
    if (c > CELLCAP) c = CELLCAP;
    unsigned* gp = rbuf + (size_t)(cell * NBINB + blk) * CELLCAP;
    const unsigned* sp = scell + cell * SCSTR;
    for (int i = sub * 4; i < c; i += 16)
      *reinterpret_cast<uint4*>(gp + i) = *reinterpret_cast<const uint4*>(sp + i);
  }
  if (tid < NREG) {
    int c = cur[tid];
    cnt2[tid * NBINB + blk] = (c > CELLCAP) ? CELLCAP : c;
  }
}

// One block per region. Sort prologue + 8-lane-group gather + MFMA matvec
// (R2-verified). Unchanged except CELLCAP geometry.
__global__ __launch_bounds__(1024) void gin_kernel(
    const float* __restrict__ feat, const ushort* __restrict__ hb,
    const float* __restrict__ W, const float* __restrict__ b,
    const float* __restrict__ eps, const int* __restrict__ cnt2,
    const unsigned* __restrict__ rbuf, float* __restrict__ out) {
  // pool: ebuf (sort phases, dead after B7) overlaid by rstH (gather onward).
  __shared__ __align__(16) char pool[MT * 16 * 72 * 2];  // 29952 B
  unsigned* ebuf = reinterpret_cast<unsigned*>(pool);    // [RECAP] = 18432 B
  ushort* rstH = reinterpret_cast<ushort*>(pool);        // [208][72] bf16
  __shared__ ushort sorted[RECAP];                       // 9 KB
  __shared__ ushort WbH[8 * 64 * 8];                     // 8 KB  B-frag hi
  __shared__ ushort WbL[8 * 64 * 8];                     // 8 KB  B-frag lo
  __shared__ float b_lds[D];
  __shared__ int cellstart[NBINB + 1];
  __shared__ int hist[RSZ], nstart[RSZ + 1], cursor[RSZ];
  __shared__ int wsum[4], wsum2[4];
  __shared__ int wq;  // dynamic node queue head

  int tid = threadIdx.x, r = blockIdx.x;
  int lane = tid & 63, wv = tid >> 6;

  // Pack W into MFMA B-fragment order, split hi/lo bf16 (W eff. fp32).
  // frag (tk,tn): lane l, elem e -> k=tk*32+(l>>4)*8+e, n=tn*16+(l&15).
  if (tid < 512) {
    int tile = tid >> 6, l = tid & 63;
    int tk = tile >> 2, tn = tile & 3;
    int n = tn * 16 + (l & 15);
    int kb = tk * 32 + ((l >> 4) << 3);
    const float4 w0 = *reinterpret_cast<const float4*>(W + (n << 6) + kb);
    const float4 w1 = *reinterpret_cast<const float4*>(W + (n << 6) + kb + 4);
    float wf[8] = {w0.x, w0.y, w0.z, w0.w, w1.x, w1.y, w1.z, w1.w};
    ushort hh[8], ll[8];
#pragma unroll
    for (int e = 0; e < 8; ++e) {
      ushort h = to_bf16(wf[e]);
      hh[e] = h;
      ll[e] = to_bf16(wf[e] - bf_val(h));
    }
    uint4 vH, vL;
    vH.x = hh[0] | ((unsigned)hh[1] << 16); vH.y = hh[2] | ((unsigned)hh[3] << 16);
    vH.z = hh[4] | ((unsigned)hh[5] << 16); vH.w = hh[6] | ((unsigned)hh[7] << 16);
    vL.x = ll[0] | ((unsigned)ll[1] << 16); vL.y = ll[2] | ((unsigned)ll[3] << 16);
    vL.z = ll[4] | ((unsigned)ll[5] << 16); vL.w = ll[6] | ((unsigned)ll[7] << 16);
    *reinterpret_cast<uint4*>(&WbH[(tile * 64 + l) * 8]) = vH;
    *reinterpret_cast<uint4*>(&WbL[(tile * 64 + l) * 8]) = vL;
  }
  if (tid < D) b_lds[tid] = b[tid];
  if (tid < RSZ) hist[tid] = 0;
  if (tid == 0) wq = 0;

  // ---- scan 1: cell counts ----
  int c = (tid < NBINB) ? cnt2[r * NBINB + tid] : 0;
  int inc = c;
#pragma unroll
  for (int dlt = 1; dlt < 64; dlt <<= 1) {
    int t = __shfl_up(inc, (unsigned)dlt, 64);
    if (lane >= dlt) inc += t;
  }
  if (tid < 256 && lane == 63) wsum[wv] = inc;
  __syncthreads();  // B1
  if (tid < 256) {
    int prefix = inc - c;
    if (wv > 0) prefix += wsum[0];
    if (wv > 1) prefix += wsum[1];
    if (wv > 2) prefix += wsum[2];
    if (tid < NBINB) cellstart[tid] = prefix;
  }
  if (tid == 0) cellstart[NBINB] = wsum[0] + wsum[1] + wsum[2] + wsum[3];
  __syncthreads();  // B2
  int T = cellstart[NBINB];
  if (T > RECAP) T = RECAP;

  {  // Concatenate cells into ebuf: 4 threads per cell, uint4 loads.
    int cell = tid >> 2, sub = tid & 3;
    if (cell < NBINB) {
      int cs = cellstart[cell];
      int cc = cellstart[cell + 1] - cs;
      const unsigned* cp = rbuf + (size_t)(r * NBINB + cell) * CELLCAP;
      for (int i = sub * 4; i < cc; i += 16) {
        uint4 v = *reinterpret_cast<const uint4*>(cp + i);
        if (cs + i + 0 < T && i + 0 < cc) ebuf[cs + i + 0] = v.x;
        if (cs + i + 1 < T && i + 1 < cc) ebuf[cs + i + 1] = v.y;
        if (cs + i + 2 < T && i + 2 < cc) ebuf[cs + i + 2] = v.z;
        if (cs + i + 3 < T && i + 3 < cc) ebuf[cs + i + 3] = v.w;
      }
    }
  }
  __syncthreads();  // B3

  for (int e = tid; e < T; e += 1024) atomicAdd(&hist[ebuf[e] >> 16], 1);
  __syncthreads();  // B4

  // ---- scan 2: node counts ----
  int h = (tid < RSZ) ? hist[tid] : 0;
  int inc2 = h;
#pragma unroll
  for (int dlt = 1; dlt < 64; dlt <<= 1) {
    int t = __shfl_up(inc2, (unsigned)dlt, 64);
    if (lane >= dlt) inc2 += t;
  }
  if (tid < 256 && lane == 63) wsum2[wv] = inc2;
  __syncthreads();  // B5
  if (tid < 256) {
    int prefix = inc2 - h;
    if (wv > 0) prefix += wsum2[0];
    if (wv > 1) prefix += wsum2[1];
    if (wv > 2) prefix += wsum2[2];
    if (tid < RSZ) {
      nstart[tid] = prefix;
      cursor[tid] = prefix;
    }
  }
  if (tid == 0) nstart[RSZ] = wsum2[0] + wsum2[1] + wsum2[2] + wsum2[3];
  __syncthreads();  // B6
  for (int e = tid; e < T; e += 1024) {
    unsigned pk = ebuf[e];
    int p = atomicAdd(&cursor[pk >> 16], 1);
    sorted[p] = (ushort)(pk & 0xFFFFu);
  }
  __syncthreads();  // B7 — ebuf dead from here; rstH takes over the pool

  // 128 groups x 8 lanes; lane owns feature slots j8..j8+7.
  int j8 = (tid & 7) << 3;
  float s = 1.0f + eps[0];

  for (;;) {
    int n = 0;
    if ((tid & 7) == 0) n = atomicAdd(&wq, 1);
    n = __shfl(n, 0, 8);
    if (n >= RSZ) break;

    int node = r * RSZ + n;
    if (node >= N_NODES) continue;  // region 255 tail (rows guarded at store)

    float acc[8];
    {  // self term in fp32
      const float4 fa = *reinterpret_cast<const float4*>(feat + (node << 6) + j8);
      const float4 fb = *reinterpret_cast<const float4*>(feat + (node << 6) + j8 + 4);
      acc[0] = s * fa.x; acc[1] = s * fa.y; acc[2] = s * fa.z; acc[3] = s * fa.w;
      acc[4] = s * fb.x; acc[5] = s * fb.y; acc[6] = s * fb.z; acc[7] = s * fb.w;
    }

    int e = nstart[n], e1 = nstart[n + 1];
    for (; e + 8 <= e1; e += 8) {
      int i0 = sorted[e + 0], i1 = sorted[e + 1], i2 = sorted[e + 2], i3 = sorted[e + 3];
      int i4_ = sorted[e + 4], i5 = sorted[e + 5], i6 = sorted[e + 6], i7 = sorted[e + 7];
      const uint4 h0 = *reinterpret_cast<const uint4*>(hb + (i0 << 6) + j8);
      const uint4 h1 = *reinterpret_cast<const uint4*>(hb + (i1 << 6) + j8);
      const uint4 h2 = *reinterpret_cast<const uint4*>(hb + (i2 << 6) + j8);
      const uint4 h3 = *reinterpret_cast<const uint4*>(hb + (i3 << 6) + j8);
      const uint4 h4 = *reinterpret_cast<const uint4*>(hb + (i4_ << 6) + j8);
      const uint4 h5 = *reinterpret_cast<const uint4*>(hb + (i5 << 6) + j8);
      const uint4 h6 = *reinterpret_cast<const uint4*>(hb + (i6 << 6) + j8);
      const uint4 h7 = *reinterpret_cast<const uint4*>(hb + (i7 << 6) + j8);
      acc[0] += (bf_lo(h0.x) + bf_lo(h1.x)) + (bf_lo(h2.x) + bf_lo(h3.x))
              + (bf_lo(h4.x) + bf_lo(h5.x)) + (bf_lo(h6.x) + bf_lo(h7.x));
      acc[1] += (bf_hi(h0.x) + bf_hi(h1.x)) + (bf_hi(h2.x) + bf_hi(h3.x))
              + (bf_hi(h4.x) + bf_hi(h5.x)) + (bf_hi(h6.x) + bf_hi(h7.x));
      acc[2] += (bf_lo(h0.y) + bf_lo(h1.y)) + (bf_lo(h2.y) + bf_lo(h3.y))
              + (bf_lo(h4.y) + bf_lo(h5.y)) + (bf_lo(h6.y) + bf_lo(h7.y));
      acc[3] += (bf_hi(h0.y) + bf_hi(h1.y)) + (bf_hi(h2.y) + bf_hi(h3.y))
              + (bf_hi(h4.y) + bf_hi(h5.y)) + (bf_hi(h6.y) + bf_hi(h7.y));
      acc[4] += (bf_lo(h0.z) + bf_lo(h1.z)) + (bf_lo(h2.z) + bf_lo(h3.z))
              + (bf_lo(h4.z) + bf_lo(h5.z)) + (bf_lo(h6.z) + bf_lo(h7.z));
      acc[5] += (bf_hi(h0.z) + bf_hi(h1.z)) + (bf_hi(h2.z) + bf_hi(h3.z))
              + (bf_hi(h4.z) + bf_hi(h5.z)) + (bf_hi(h6.z) + bf_hi(h7.z));
      acc[6] += (bf_lo(h0.w) + bf_lo(h1.w)) + (bf_lo(h2.w) + bf_lo(h3.w))
              + (bf_lo(h4.w) + bf_lo(h5.w)) + (bf_lo(h6.w) + bf_lo(h7.w));
      acc[7] += (bf_hi(h0.w) + bf_hi(h1.w)) + (bf_hi(h2.w) + bf_hi(h3.w))
              + (bf_hi(h4.w) + bf_hi(h5.w)) + (bf_hi(h6.w) + bf_hi(h7.w));
    }
    for (; e < e1; ++e) {
      int sn = sorted[e];
      const uint4 hv = *reinterpret_cast<const uint4*>(hb + (sn << 6) + j8);
      acc[0] += bf_lo(hv.x); acc[1] += bf_hi(hv.x);
      acc[2] += bf_lo(hv.y); acc[3] += bf_hi(hv.y);
      acc[4] += bf_lo(hv.z); acc[5] += bf_hi(hv.z);
      acc[6] += bf_lo(hv.w); acc[7] += bf_hi(hv.w);
    }

    // Store rst row slice as bf16 (A-fragment-friendly; row stride 144B).
    unsigned p0 = (unsigned)to_bf16(acc[0]) | ((unsigned)to_bf16(acc[1]) << 16);
    unsigned p1 = (unsigned)to_bf16(acc[2]) | ((unsigned)to_bf16(acc[3]) << 16);
    unsigned p2 = (unsigned)to_bf16(acc[4]) | ((unsigned)to_bf16(acc[5]) << 16);
    unsigned p3 = (unsigned)to_bf16(acc[6]) | ((unsigned)to_bf16(acc[7]) << 16);
    uint4 vv; vv.x = p0; vv.y = p1; vv.z = p2; vv.w = p3;
    *reinterpret_cast<uint4*>(&rstH[n * 72 + j8]) = vv;
  }
  __syncthreads();  // B8 — all rst rows written

  // ---- MFMA phase: out[196x64] = rst @ (WH + WL) + b ----
  {
    int l = tid & 63;
    int lr = l & 15, lc = l >> 4;
    for (int t = wv; t < MT * 4; t += 16) {
      int mt = t >> 2, nt = t & 3;
      int m0 = mt << 4, n0 = nt << 4;
      float bc = b_lds[n0 + lr];
      f32x4 cacc = {bc, bc, bc, bc};
#pragma unroll
      for (int tk = 0; tk < 2; ++tk) {
        short8v a = *reinterpret_cast<const short8v*>(&rstH[(m0 + lr) * 72 + tk * 32 + lc * 8]);
        short8v wh = *reinterpret_cast<const short8v*>(&WbH[((tk * 4 + nt) * 64 + l) * 8]);
        short8v wl = *reinterpret_cast<const short8v*>(&WbL[((tk * 4 + nt) * 64 + l) * 8]);
        cacc = __builtin_amdgcn_mfma_f32_16x16x32_bf16(a, wh, cacc, 0, 0, 0);
        cacc = __builtin_amdgcn_mfma_f32_16x16x32_bf16(a, wl, cacc, 0, 0, 0);
      }
#pragma unroll
      for (int rr = 0; rr < 4; ++rr) {
        int row = m0 + lc * 4 + rr;  // C/D: col=lane&15, row=(lane>>4)*4+reg (m89)
        int node = r * RSZ + row;
        if (row < RSZ && node < N_NODES)
          out[(node << 6) + n0 + lr] = cacc[rr];
      }
    }
  }
}

extern "C" void kernel_launch(void* const* d_in, const int* in_sizes, int n_in,
                              void* d_out, int out_size, void* d_ws, size_t ws_size,
                              hipStream_t stream) {
  const float* feat = (const float*)d_in[0];
  const float* W    = (const float*)d_in[1];
  const float* b    = (const float*)d_in[2];
  const float* eps  = (const float*)d_in[3];
  const int*   src  = (const int*)d_in[4];
  const int*   dst  = (const int*)d_in[5];
  float* out = (float*)d_out;

  int* ws = (int*)d_ws;
  int* cnt2      = ws + WS_CNT2;
  unsigned* rbuf = (unsigned*)(ws + WS_RBUF);
  ushort* hb     = (ushort*)((char*)d_ws + WS_HB_BYTE);

  hipLaunchKernelGGL(prep_kernel, dim3(NBINB), dim3(1024), 0, stream,
                     (const float4*)feat, src, dst, hb, cnt2, rbuf);
  hipLaunchKernelGGL(gin_kernel, dim3(NREG), dim3(1024), 0, stream,
                     feat, hb, W, b, eps, cnt2, rbuf, out);
}